// Round 10
// baseline (129.871 us; speedup 1.0000x reference)
//
#include <hip/hip_runtime.h>
#include <math.h>

// NaiveDFTQNN: 25-wire state vector, DIM = 2^25.
// out = (cos(theta[0]/2)/||f||) * (tensor product of 12 Givens rotations) * f
// Pair j (j=0..11) acts on little-endian element bits (2j+1, 2j), angle theta[11-j]/2:
//   v=01: n01 = c*a01 - s*a10 ; v=10: n10 = s*a01 + c*a10 ; v=00,11 untouched.
// Bit 24 (wire 0) is a spectator (RX folds into the scalar).
//
// qnn_p1:  j0..j6 (el bits 0..13) + sumsq, in -> out. NT-load in, regular store
//          (intermediate stays IC-resident). 256 thr x 16 quads, 32 KB LDS via a
//          2-round exchange (partition bit sigma[9]) -> 4 blocks/CU (16 waves).
// qnn_high: j7..j11 (el bits 14..23) + scale, out in place. 512 thr x 16 quads
//          x 2 tiles (b24=0/1), 128 KB LDS, 1 LDS trip, NT final store.
// Barriers are lgkm-only (global loads stay in flight across them).

typedef float f32x4 __attribute__((ext_vector_type(4)));

static __device__ __forceinline__ float4 nt_load4(const float* p) {
    f32x4 v = __builtin_nontemporal_load((const f32x4*)p);
    return *(float4*)&v;
}
static __device__ __forceinline__ void nt_store4(float* p, float4 v) {
    __builtin_nontemporal_store(*(f32x4*)&v, (f32x4*)p);
}

// Barrier that drains ONLY lgkmcnt (LDS) — global loads/stores stay in flight.
static __device__ __forceinline__ void bar_lgkm() {
    asm volatile("s_waitcnt lgkmcnt(0)\n\ts_barrier" ::: "memory");
}

static __device__ __forceinline__ void rot4(float4& a, float4& b, float c, float s) {
    float4 na, nb;
    na.x = c*a.x - s*b.x;  nb.x = s*a.x + c*b.x;
    na.y = c*a.y - s*b.y;  nb.y = s*a.y + c*b.y;
    na.z = c*a.z - s*b.z;  nb.z = s*a.z + c*b.z;
    na.w = c*a.w - s*b.w;  nb.w = s*a.w + c*b.w;
    a = na; b = nb;
}

static __device__ __forceinline__ float4 shflx4(float4 v, int m) {
    float4 r;
    r.x = __shfl_xor(v.x, m, 64);
    r.y = __shfl_xor(v.y, m, 64);
    r.z = __shfl_xor(v.z, m, 64);
    r.w = __shfl_xor(v.w, m, 64);
    return r;
}

template <int NR>
static __device__ __forceinline__ void rotshfl(float4* f, int sh, float c, float s, int lane) {
    const int pv = (lane >> sh) & 3;
    const bool act = (pv == 1) || (pv == 2);
    const float cl = act ? c : 1.0f;
    const float sl = act ? ((pv == 1) ? -s : s) : 0.0f;
    const int m = 3 << sh;
#pragma unroll
    for (int k = 0; k < NR; ++k) {
        float4 p = shflx4(f[k], m);
        float4 n;
        n.x = fmaf(sl, p.x, cl * f[k].x);
        n.y = fmaf(sl, p.y, cl * f[k].y);
        n.z = fmaf(sl, p.z, cl * f[k].z);
        n.w = fmaf(sl, p.w, cl * f[k].w);
        f[k] = n;
    }
}

// ---------------- qnn_p1: pairs j0..j6 (el bits 0..13), in -> out, + partials ------
// Tile = contiguous 4096 quads; tile slot sigma (12 bits) = el bits 2..13.
// Load layout  sigma = w2<<10 | k<<6 | lane  (w2 = t>>6, k = 0..15):
//   j0 components; j1/j2/j3 lane shfl (sigma 1,0/3,2/5,4); j4 = k[1:0] (sigma 7,6);
//   j5 = k[3:2] (sigma 9,8).
// Exchange to sigma = m<<8 | w2<<6 | lane (j6 = sigma 11,10 = m[3:2]) through a
// 2048-slot buffer: addr(sigma) = sigma[11:10]<<9 | sigma[8]<<8 | sigma[7:6]<<6
// | sigma[5:0]  (partition bit sigma[9]: writer k[3], reader m[1]).
// Round 0: write k=0..7, read m in {0,1,4,5,8,9,12,13} into f[0..7].
// Round 1: write k=8..15, read m in {2,3,6,7,10,11,14,15} into f[8..15].
// All LDS ops lane-contiguous (conflict-free); stores 1 KB contiguous per instr.
__global__ __launch_bounds__(256, 4) void qnn_p1(const float* __restrict__ in,
                                                 const float* __restrict__ theta,
                                                 float* __restrict__ out,
                                                 double* __restrict__ partials) {
    __shared__ __align__(16) float4 lds[2048];   // 32 KB
    __shared__ double red[4];
    const int t = threadIdx.x, lane = t & 63, w2 = t >> 6;
    const long gfb = (long)blockIdx.x << 12;     // quad base

    float c0,s0,c1,s1,c2,s2,c3,s3,c4,s4,c5,s5,c6,s6;
    { float th;
      th=0.5f*theta[11]; c0=cosf(th); s0=sinf(th);
      th=0.5f*theta[10]; c1=cosf(th); s1=sinf(th);
      th=0.5f*theta[9];  c2=cosf(th); s2=sinf(th);
      th=0.5f*theta[8];  c3=cosf(th); s3=sinf(th);
      th=0.5f*theta[7];  c4=cosf(th); s4=sinf(th);
      th=0.5f*theta[6];  c5=cosf(th); s5=sinf(th);
      th=0.5f*theta[5];  c6=cosf(th); s6=sinf(th); }

    float4 f[16];
#pragma unroll
    for (int k = 0; k < 16; ++k)
        f[k] = nt_load4(in + ((gfb + ((w2 << 10) | (k << 6) | lane)) << 2));

    double acc = 0.0;
#pragma unroll
    for (int k = 0; k < 16; ++k)
        acc += (double)f[k].x*f[k].x + (double)f[k].y*f[k].y
             + (double)f[k].z*f[k].z + (double)f[k].w*f[k].w;

    // j0: el bits (1,0) = components (y,z)
#pragma unroll
    for (int k = 0; k < 16; ++k) {
        float ny = c0*f[k].y - s0*f[k].z;
        float nz = s0*f[k].y + c0*f[k].z;
        f[k].y = ny; f[k].z = nz;
    }
    rotshfl<16>(f, 0, c1, s1, lane);   // j1: sigma 1,0
    rotshfl<16>(f, 2, c2, s2, lane);   // j2: sigma 3,2
    rotshfl<16>(f, 4, c3, s3, lane);   // j3: sigma 5,4
#pragma unroll
    for (int hi = 0; hi < 16; hi += 4) rot4(f[hi+1], f[hi+2], c4, s4);   // j4
#pragma unroll
    for (int lo = 0; lo < 4; ++lo)     rot4(f[4+lo], f[8+lo], c5, s5);   // j5

    const int rb = (w2 << 6) | lane;
    // ---- exchange round 0: write k=0..7 (sigma[9]=0), read m with m[1]=0 ----
#pragma unroll
    for (int k = 0; k < 8; ++k)
        lds[(w2 << 9) | (k << 6) | lane] = f[k];
    bar_lgkm();
    f[0] = lds[rb];                         // m=0
    f[1] = lds[(1 << 8) | rb];              // m=1
    f[2] = lds[(1 << 9) | rb];              // m=4
    f[3] = lds[(1 << 9) | (1 << 8) | rb];   // m=5
    f[4] = lds[(2 << 9) | rb];              // m=8
    f[5] = lds[(2 << 9) | (1 << 8) | rb];   // m=9
    f[6] = lds[(3 << 9) | rb];              // m=12
    f[7] = lds[(3 << 9) | (1 << 8) | rb];   // m=13
    bar_lgkm();
    // ---- exchange round 1: write k=8..15 (sigma[9]=1), read m with m[1]=1 ----
#pragma unroll
    for (int k = 8; k < 16; ++k)
        lds[(w2 << 9) | ((k - 8) << 6) | lane] = f[k];
    bar_lgkm();
    f[8]  = lds[rb];                        // m=2
    f[9]  = lds[(1 << 8) | rb];             // m=3
    f[10] = lds[(1 << 9) | rb];             // m=6
    f[11] = lds[(1 << 9) | (1 << 8) | rb];  // m=7
    f[12] = lds[(2 << 9) | rb];             // m=10
    f[13] = lds[(2 << 9) | (1 << 8) | rb];  // m=11
    f[14] = lds[(3 << 9) | rb];             // m=14
    f[15] = lds[(3 << 9) | (1 << 8) | rb];  // m=15

    // j6 (sigma 11,10 = m[3:2]): pairs m (4,8),(5,9),(6,10),(7,11)
    rot4(f[2],  f[4],  c6, s6);
    rot4(f[3],  f[5],  c6, s6);
    rot4(f[10], f[12], c6, s6);
    rot4(f[11], f[13], c6, s6);

    // stores at sigma = m<<8 | w2<<6 | lane (1 KB contiguous per instruction)
    {
        const int M[16] = {0,1,4,5,8,9,12,13, 2,3,6,7,10,11,14,15};
#pragma unroll
        for (int i = 0; i < 16; ++i)
            *(float4*)(out + ((gfb + ((M[i] << 8) | rb)) << 2)) = f[i];
    }

    // deterministic sumsq partial
#pragma unroll
    for (int off = 32; off > 0; off >>= 1) acc += __shfl_down(acc, off, 64);
    if (lane == 0) red[w2] = acc;
    bar_lgkm();
    if (t == 0)
        partials[blockIdx.x] = red[0] + red[1] + red[2] + red[3];
}

// ---------------- Norm: 2048 partials -> scale = cos(theta[0]/2)/sqrt(sum) ---------
__global__ void qnn_norm(const double* __restrict__ partials,
                         const float* __restrict__ theta,
                         double* __restrict__ scale) {
    __shared__ double w[4];
    const int t = threadIdx.x;
    double acc = 0.0;
    for (int i = t; i < 2048; i += 256) acc += partials[i];
#pragma unroll
    for (int off = 32; off > 0; off >>= 1) acc += __shfl_down(acc, off, 64);
    if ((t & 63) == 0) w[t >> 6] = acc;
    __syncthreads();
    if (t == 0) {
        double tot = w[0] + w[1] + w[2] + w[3];
        *scale = (double)cosf(0.5f * theta[0]) / sqrt(tot);
    }
}

// ---------------- qnn_high: pairs j7..j11 (el bits 14..23) + scale, in place -------
// Tile: slot s (13 bits) = H<<3 | pq; H = el bits 14..23, pq = el bits 2..4.
// Global quad = b24<<22 | H<<12 | mid<<3 | pq (mid = el bits 5..13, grid 512;
// both b24 tiles per block). 128 B granules at 64 KB stride.
// Load layout s = k<<9 | t (512 thr, k=0..15): j7 = s bits 4,3 (lane shfl);
// j10 = s bits 10,9 = k bits 1,0; j11 = s bits 12,11 = k bits 3,2.
// LDS exchange to s' = w3<<10 | (lane>>5)<<9 | m<<5 | (lane&31):
// j8 = s bits 6,5 = m bits 1,0; j9 = s bits 8,7 = m bits 3,2. NT store at s'.
__global__ __launch_bounds__(512, 2) void qnn_high(float* __restrict__ buf,
                                                   const float* __restrict__ theta,
                                                   const double* __restrict__ scale) {
    __shared__ __align__(16) float4 lds[8192];   // 128 KB
    const int t = threadIdx.x, lane = t & 63, w3 = t >> 6;
    const int mid = blockIdx.x;
    const long gqA = (long)mid << 3;                 // b24 = 0
    const long gqB = (1L << 22) | ((long)mid << 3);  // b24 = 1

    float c7,s7,c8,s8,c9,s9,c10,s10,c11,s11;
    { float th;
      th=0.5f*theta[4]; c7 =cosf(th); s7 =sinf(th);
      th=0.5f*theta[3]; c8 =cosf(th); s8 =sinf(th);
      th=0.5f*theta[2]; c9 =cosf(th); s9 =sinf(th);
      th=0.5f*theta[1]; c10=cosf(th); s10=sinf(th);
      th=0.5f*theta[0]; c11=cosf(th); s11=sinf(th); }
    const float sc = (float)(*scale);

    const int rbase = (w3 << 10) | ((lane >> 5) << 9) | (lane & 31);  // read base

    float4 f[16], g[16];
    // ---- issue ALL 32 loads ----
#pragma unroll
    for (int k = 0; k < 16; ++k) {
        const int s_ = (k << 9) | t;
        f[k] = *(const float4*)(buf + ((gqA | ((long)(s_ >> 3) << 12) | (s_ & 7)) << 2));
    }
#pragma unroll
    for (int k = 0; k < 16; ++k) {
        const int s_ = (k << 9) | t;
        g[k] = *(const float4*)(buf + ((gqB | ((long)(s_ >> 3) << 12) | (s_ & 7)) << 2));
    }

    // ---- tile A: j7 (shfl), j10/j11 (regs) ----
    rotshfl<16>(f, 3, c7, s7, lane);
#pragma unroll
    for (int hi = 0; hi < 16; hi += 4) rot4(f[hi+1], f[hi+2], c10, s10);
#pragma unroll
    for (int lo = 0; lo < 4; ++lo)     rot4(f[4+lo], f[8+lo], c11, s11);
#pragma unroll
    for (int k = 0; k < 16; ++k) lds[(k << 9) | t] = f[k];
    bar_lgkm();
    // ---- read A; j8/j9 (regs); scale; NT store ----
#pragma unroll
    for (int m = 0; m < 16; ++m) f[m] = lds[rbase | (m << 5)];
#pragma unroll
    for (int hi = 0; hi < 16; hi += 4) rot4(f[hi+1], f[hi+2], c8, s8);
#pragma unroll
    for (int lo = 0; lo < 4; ++lo)     rot4(f[4+lo], f[8+lo], c9, s9);
#pragma unroll
    for (int m = 0; m < 16; ++m) {
        const int s_ = rbase | (m << 5);
        float4 v = f[m];
        v.x *= sc; v.y *= sc; v.z *= sc; v.w *= sc;
        nt_store4(buf + ((gqA | ((long)(s_ >> 3) << 12) | (s_ & 7)) << 2), v);
    }

    // ---- tile B ----
    rotshfl<16>(g, 3, c7, s7, lane);
#pragma unroll
    for (int hi = 0; hi < 16; hi += 4) rot4(g[hi+1], g[hi+2], c10, s10);
#pragma unroll
    for (int lo = 0; lo < 4; ++lo)     rot4(g[4+lo], g[8+lo], c11, s11);
    bar_lgkm();   // all waves done reading A's LDS image
#pragma unroll
    for (int k = 0; k < 16; ++k) lds[(k << 9) | t] = g[k];
    bar_lgkm();
#pragma unroll
    for (int m = 0; m < 16; ++m) g[m] = lds[rbase | (m << 5)];
#pragma unroll
    for (int hi = 0; hi < 16; hi += 4) rot4(g[hi+1], g[hi+2], c8, s8);
#pragma unroll
    for (int lo = 0; lo < 4; ++lo)     rot4(g[4+lo], g[8+lo], c9, s9);
#pragma unroll
    for (int m = 0; m < 16; ++m) {
        const int s_ = rbase | (m << 5);
        float4 v = g[m];
        v.x *= sc; v.y *= sc; v.z *= sc; v.w *= sc;
        nt_store4(buf + ((gqB | ((long)(s_ >> 3) << 12) | (s_ & 7)) << 2), v);
    }
}

extern "C" void kernel_launch(void* const* d_in, const int* in_sizes, int n_in,
                              void* d_out, int out_size, void* d_ws, size_t ws_size,
                              hipStream_t stream) {
    const float* in = (const float*)d_in[0];      // feature, 2^25 f32
    const float* theta = (const float*)d_in[1];   // 13 f32
    float* out = (float*)d_out;                   // 2^25 f32
    double* part = (double*)d_ws;                 // 2048 partials + 1 scale
    double* scale = part + 2048;

    qnn_p1<<<2048, 256, 0, stream>>>(in, theta, out, part);
    qnn_norm<<<1, 256, 0, stream>>>(part, theta, scale);
    qnn_high<<<512, 512, 0, stream>>>(out, theta, scale);
}

// Round 11
// 118.863 us; speedup vs baseline: 1.0926x; 1.0926x over previous
//
#include <hip/hip_runtime.h>
#include <math.h>

// NaiveDFTQNN: 25-wire state vector, DIM = 2^25.
// out = (cos(theta[0]/2)/||f||) * (tensor product of 12 Givens rotations) * f
// Pair j (j=0..11) acts on little-endian element bits (2j+1, 2j), angle theta[11-j]/2:
//   v=01: n01 = c*a01 - s*a10 ; v=10: n10 = s*a01 + c*a10 ; v=00,11 untouched.
// Bit 24 (wire 0) is a spectator (RX folds into the scalar).
//
// Cache steering (r10 lesson: WRITE amplification = IC capacity fight between
// `in` and the write-allocated intermediate):
//   - `in` is REGULAR-loaded -> IC-resident across replays (constant data,
//     nothing else allocates; p1 reads at IC rate after warmup).
//   - intermediate is NT-stored by p1 and NT-loaded by high (streams HBM,
//     never allocates, never evicts `in`).
//   - final result NT-stored.
// Schedules are r9's best-known: p1 = 256 thr x 16 quads x 2 tiles, 32 loads
// issued upfront (MLP-limited, keep depth 32), 64 KB LDS, lgkm-only barriers;
// high = 512 thr x 16 quads x 2 tiles (b24=0/1), 128 KB LDS, 1 LDS trip.

typedef float f32x4 __attribute__((ext_vector_type(4)));

static __device__ __forceinline__ float4 nt_load4(const float* p) {
    f32x4 v = __builtin_nontemporal_load((const f32x4*)p);
    return *(float4*)&v;
}
static __device__ __forceinline__ void nt_store4(float* p, float4 v) {
    __builtin_nontemporal_store(*(f32x4*)&v, (f32x4*)p);
}

// Barrier that drains ONLY lgkmcnt (LDS) — global loads/stores stay in flight.
static __device__ __forceinline__ void bar_lgkm() {
    asm volatile("s_waitcnt lgkmcnt(0)\n\ts_barrier" ::: "memory");
}

static __device__ __forceinline__ void rot4(float4& a, float4& b, float c, float s) {
    float4 na, nb;
    na.x = c*a.x - s*b.x;  nb.x = s*a.x + c*b.x;
    na.y = c*a.y - s*b.y;  nb.y = s*a.y + c*b.y;
    na.z = c*a.z - s*b.z;  nb.z = s*a.z + c*b.z;
    na.w = c*a.w - s*b.w;  nb.w = s*a.w + c*b.w;
    a = na; b = nb;
}

static __device__ __forceinline__ float4 shflx4(float4 v, int m) {
    float4 r;
    r.x = __shfl_xor(v.x, m, 64);
    r.y = __shfl_xor(v.y, m, 64);
    r.z = __shfl_xor(v.z, m, 64);
    r.w = __shfl_xor(v.w, m, 64);
    return r;
}

template <int NR>
static __device__ __forceinline__ void rotshfl(float4* f, int sh, float c, float s, int lane) {
    const int pv = (lane >> sh) & 3;
    const bool act = (pv == 1) || (pv == 2);
    const float cl = act ? c : 1.0f;
    const float sl = act ? ((pv == 1) ? -s : s) : 0.0f;
    const int m = 3 << sh;
#pragma unroll
    for (int k = 0; k < NR; ++k) {
        float4 p = shflx4(f[k], m);
        float4 n;
        n.x = fmaf(sl, p.x, cl * f[k].x);
        n.y = fmaf(sl, p.y, cl * f[k].y);
        n.z = fmaf(sl, p.z, cl * f[k].z);
        n.w = fmaf(sl, p.w, cl * f[k].w);
        f[k] = n;
    }
}

// ---------------- qnn_p1: pairs j0..j6 (el bits 0..13), in -> out, + partials ------
// Tile = contiguous 4096 quads (s bits 0..11 = el bits 2..13); 2 tiles/block.
// Load layout  s = w2<<10 | k<<6 | lane: j0 components; j1/j2/j3 lane shfl
// (s bits 1,0/3,2/5,4); j4 = k bits 1,0; j5 = k bits 3,2.
// LDS exchange to s' = m<<8 | w2<<6 | lane: j6 = m bits 3,2. NT store at s'.
// Pipeline: loadA,loadB | rotA,writeA | BAR | readA,j6A,storeA,rotB | BAR |
//           writeB | BAR | readB,j6B,storeB.  (BAR = lgkm-only)
__global__ __launch_bounds__(256, 2) void qnn_p1(const float* __restrict__ in,
                                                 const float* __restrict__ theta,
                                                 float* __restrict__ out,
                                                 double* __restrict__ partials) {
    __shared__ __align__(16) float4 lds[4096];   // 64 KB
    __shared__ double red[4];
    const int t = threadIdx.x, lane = t & 63, w2 = t >> 6;
    const long gA = (long)blockIdx.x << 13;      // quad base, tile A
    const long gB = gA + 4096;                   // tile B

    float c0,s0,c1,s1,c2,s2,c3,s3,c4,s4,c5,s5,c6,s6;
    { float th;
      th=0.5f*theta[11]; c0=cosf(th); s0=sinf(th);
      th=0.5f*theta[10]; c1=cosf(th); s1=sinf(th);
      th=0.5f*theta[9];  c2=cosf(th); s2=sinf(th);
      th=0.5f*theta[8];  c3=cosf(th); s3=sinf(th);
      th=0.5f*theta[7];  c4=cosf(th); s4=sinf(th);
      th=0.5f*theta[6];  c5=cosf(th); s5=sinf(th);
      th=0.5f*theta[5];  c6=cosf(th); s6=sinf(th); }

    float4 f[16], g[16];
    // ---- issue ALL 32 loads (regular: keep `in` IC-resident across replays) ----
#pragma unroll
    for (int k = 0; k < 16; ++k)
        f[k] = *(const float4*)(in + ((gA + ((w2 << 10) | (k << 6) | lane)) << 2));
#pragma unroll
    for (int k = 0; k < 16; ++k)
        g[k] = *(const float4*)(in + ((gB + ((w2 << 10) | (k << 6) | lane)) << 2));

    double acc = 0.0;
#pragma unroll
    for (int k = 0; k < 16; ++k)
        acc += (double)f[k].x*f[k].x + (double)f[k].y*f[k].y
             + (double)f[k].z*f[k].z + (double)f[k].w*f[k].w;

    // ---- tile A: register rotations j0..j5 ----
#pragma unroll
    for (int k = 0; k < 16; ++k) {
        float ny = c0*f[k].y - s0*f[k].z;
        float nz = s0*f[k].y + c0*f[k].z;
        f[k].y = ny; f[k].z = nz;
    }
    rotshfl<16>(f, 0, c1, s1, lane);
    rotshfl<16>(f, 2, c2, s2, lane);
    rotshfl<16>(f, 4, c3, s3, lane);
#pragma unroll
    for (int hi = 0; hi < 16; hi += 4) rot4(f[hi+1], f[hi+2], c4, s4);
#pragma unroll
    for (int lo = 0; lo < 4; ++lo)     rot4(f[4+lo], f[8+lo], c5, s5);

#pragma unroll
    for (int k = 0; k < 16; ++k) lds[(w2 << 10) | (k << 6) | lane] = f[k];
    bar_lgkm();
    // ---- read A at s' = m<<8 | w2<<6 | lane; j6 = m bits 3,2; NT store ----
#pragma unroll
    for (int m = 0; m < 16; ++m) f[m] = lds[(m << 8) | (w2 << 6) | lane];
#pragma unroll
    for (int lo = 0; lo < 4; ++lo) rot4(f[4+lo], f[8+lo], c6, s6);
#pragma unroll
    for (int m = 0; m < 16; ++m)
        nt_store4(out + ((gA + ((m << 8) | (w2 << 6) | lane)) << 2), f[m]);

    // ---- tile B register rotations (loads long since landed) ----
#pragma unroll
    for (int k = 0; k < 16; ++k)
        acc += (double)g[k].x*g[k].x + (double)g[k].y*g[k].y
             + (double)g[k].z*g[k].z + (double)g[k].w*g[k].w;
#pragma unroll
    for (int k = 0; k < 16; ++k) {
        float ny = c0*g[k].y - s0*g[k].z;
        float nz = s0*g[k].y + c0*g[k].z;
        g[k].y = ny; g[k].z = nz;
    }
    rotshfl<16>(g, 0, c1, s1, lane);
    rotshfl<16>(g, 2, c2, s2, lane);
    rotshfl<16>(g, 4, c3, s3, lane);
#pragma unroll
    for (int hi = 0; hi < 16; hi += 4) rot4(g[hi+1], g[hi+2], c4, s4);
#pragma unroll
    for (int lo = 0; lo < 4; ++lo)     rot4(g[4+lo], g[8+lo], c5, s5);

    bar_lgkm();   // all waves done reading A's LDS image
#pragma unroll
    for (int k = 0; k < 16; ++k) lds[(w2 << 10) | (k << 6) | lane] = g[k];
    bar_lgkm();
#pragma unroll
    for (int m = 0; m < 16; ++m) g[m] = lds[(m << 8) | (w2 << 6) | lane];
#pragma unroll
    for (int lo = 0; lo < 4; ++lo) rot4(g[4+lo], g[8+lo], c6, s6);
#pragma unroll
    for (int m = 0; m < 16; ++m)
        nt_store4(out + ((gB + ((m << 8) | (w2 << 6) | lane)) << 2), g[m]);

    // ---- deterministic sumsq partial ----
#pragma unroll
    for (int off = 32; off > 0; off >>= 1) acc += __shfl_down(acc, off, 64);
    if (lane == 0) red[w2] = acc;
    bar_lgkm();
    if (t == 0)
        partials[blockIdx.x] = red[0] + red[1] + red[2] + red[3];
}

// ---------------- Norm: 1024 partials -> scale = cos(theta[0]/2)/sqrt(sum) ---------
__global__ void qnn_norm(const double* __restrict__ partials,
                         const float* __restrict__ theta,
                         double* __restrict__ scale) {
    __shared__ double w[4];
    const int t = threadIdx.x;
    double acc = 0.0;
    for (int i = t; i < 1024; i += 256) acc += partials[i];
#pragma unroll
    for (int off = 32; off > 0; off >>= 1) acc += __shfl_down(acc, off, 64);
    if ((t & 63) == 0) w[t >> 6] = acc;
    __syncthreads();
    if (t == 0) {
        double tot = w[0] + w[1] + w[2] + w[3];
        *scale = (double)cosf(0.5f * theta[0]) / sqrt(tot);
    }
}

// ---------------- qnn_high: pairs j7..j11 (el bits 14..23) + scale, in place -------
// Tile: slot s (13 bits) = H<<3 | pq; H = el bits 14..23, pq = el bits 2..4.
// Global quad = b24<<22 | H<<12 | mid<<3 | pq (mid = el bits 5..13, grid 512;
// both b24 tiles per block). 128 B granules at 64 KB stride.
// Load layout s = k<<9 | t (512 thr, k=0..15): j7 = s bits 4,3 (lane shfl);
// j10 = s bits 10,9 = k bits 1,0; j11 = s bits 12,11 = k bits 3,2.
// LDS exchange to s' = w3<<10 | (lane>>5)<<9 | m<<5 | (lane&31):
// j8 = s bits 6,5 = m bits 1,0; j9 = s bits 8,7 = m bits 3,2. NT store at s'.
// All loads NT (read-once stream; don't evict IC-resident `in`).
__global__ __launch_bounds__(512, 2) void qnn_high(float* __restrict__ buf,
                                                   const float* __restrict__ theta,
                                                   const double* __restrict__ scale) {
    __shared__ __align__(16) float4 lds[8192];   // 128 KB
    const int t = threadIdx.x, lane = t & 63, w3 = t >> 6;
    const int mid = blockIdx.x;
    const long gqA = (long)mid << 3;                 // b24 = 0
    const long gqB = (1L << 22) | ((long)mid << 3);  // b24 = 1

    float c7,s7,c8,s8,c9,s9,c10,s10,c11,s11;
    { float th;
      th=0.5f*theta[4]; c7 =cosf(th); s7 =sinf(th);
      th=0.5f*theta[3]; c8 =cosf(th); s8 =sinf(th);
      th=0.5f*theta[2]; c9 =cosf(th); s9 =sinf(th);
      th=0.5f*theta[1]; c10=cosf(th); s10=sinf(th);
      th=0.5f*theta[0]; c11=cosf(th); s11=sinf(th); }
    const float sc = (float)(*scale);

    const int rbase = (w3 << 10) | ((lane >> 5) << 9) | (lane & 31);  // read base

    float4 f[16], g[16];
    // ---- issue ALL 32 NT loads ----
#pragma unroll
    for (int k = 0; k < 16; ++k) {
        const int s_ = (k << 9) | t;
        f[k] = nt_load4(buf + ((gqA | ((long)(s_ >> 3) << 12) | (s_ & 7)) << 2));
    }
#pragma unroll
    for (int k = 0; k < 16; ++k) {
        const int s_ = (k << 9) | t;
        g[k] = nt_load4(buf + ((gqB | ((long)(s_ >> 3) << 12) | (s_ & 7)) << 2));
    }

    // ---- tile A: j7 (shfl), j10/j11 (regs) ----
    rotshfl<16>(f, 3, c7, s7, lane);
#pragma unroll
    for (int hi = 0; hi < 16; hi += 4) rot4(f[hi+1], f[hi+2], c10, s10);
#pragma unroll
    for (int lo = 0; lo < 4; ++lo)     rot4(f[4+lo], f[8+lo], c11, s11);
#pragma unroll
    for (int k = 0; k < 16; ++k) lds[(k << 9) | t] = f[k];
    bar_lgkm();
    // ---- read A; j8/j9 (regs); scale; NT store ----
#pragma unroll
    for (int m = 0; m < 16; ++m) f[m] = lds[rbase | (m << 5)];
#pragma unroll
    for (int hi = 0; hi < 16; hi += 4) rot4(f[hi+1], f[hi+2], c8, s8);
#pragma unroll
    for (int lo = 0; lo < 4; ++lo)     rot4(f[4+lo], f[8+lo], c9, s9);
#pragma unroll
    for (int m = 0; m < 16; ++m) {
        const int s_ = rbase | (m << 5);
        float4 v = f[m];
        v.x *= sc; v.y *= sc; v.z *= sc; v.w *= sc;
        nt_store4(buf + ((gqA | ((long)(s_ >> 3) << 12) | (s_ & 7)) << 2), v);
    }

    // ---- tile B ----
    rotshfl<16>(g, 3, c7, s7, lane);
#pragma unroll
    for (int hi = 0; hi < 16; hi += 4) rot4(g[hi+1], g[hi+2], c10, s10);
#pragma unroll
    for (int lo = 0; lo < 4; ++lo)     rot4(g[4+lo], g[8+lo], c11, s11);
    bar_lgkm();   // all waves done reading A's LDS image
#pragma unroll
    for (int k = 0; k < 16; ++k) lds[(k << 9) | t] = g[k];
    bar_lgkm();
#pragma unroll
    for (int m = 0; m < 16; ++m) g[m] = lds[rbase | (m << 5)];
#pragma unroll
    for (int hi = 0; hi < 16; hi += 4) rot4(g[hi+1], g[hi+2], c8, s8);
#pragma unroll
    for (int lo = 0; lo < 4; ++lo)     rot4(g[4+lo], g[8+lo], c9, s9);
#pragma unroll
    for (int m = 0; m < 16; ++m) {
        const int s_ = rbase | (m << 5);
        float4 v = g[m];
        v.x *= sc; v.y *= sc; v.z *= sc; v.w *= sc;
        nt_store4(buf + ((gqB | ((long)(s_ >> 3) << 12) | (s_ & 7)) << 2), v);
    }
}

extern "C" void kernel_launch(void* const* d_in, const int* in_sizes, int n_in,
                              void* d_out, int out_size, void* d_ws, size_t ws_size,
                              hipStream_t stream) {
    const float* in = (const float*)d_in[0];      // feature, 2^25 f32
    const float* theta = (const float*)d_in[1];   // 13 f32
    float* out = (float*)d_out;                   // 2^25 f32
    double* part = (double*)d_ws;                 // 1024 partials + 1 scale
    double* scale = part + 1024;

    qnn_p1<<<1024, 256, 0, stream>>>(in, theta, out, part);
    qnn_norm<<<1, 256, 0, stream>>>(part, theta, scale);
    qnn_high<<<512, 512, 0, stream>>>(out, theta, scale);
}